// Round 10
// baseline (849.846 us; speedup 1.0000x reference)
//
#include <hip/hip_runtime.h>
#include <hip/hip_bf16.h>

typedef unsigned int u32;
typedef unsigned short u16;
typedef __attribute__((ext_vector_type(8))) short bf16x8;
typedef __attribute__((ext_vector_type(4))) float f32x4;

// Problem constants
#define NWORDS 4096   // B*S
#define CC 32         // chars per word
#define EE 128        // embed dim
#define HHH 256       // hidden
#define MMW 64        // words per block (4 m-tiles per wave)
#define VOCABN 262

// LDS row strides chosen so stride(dwords) % 32 == 8 -> low-way b128 conflicts
#define HS 272        // u16 stride for h arrays (136 dw, 136%32=8)
#define XS 144        // u16 stride for x array  (72 dw,  72%32=8)

// Packed-weight workspace layout (u16 units), per direction:
//   HH: frag[(nt*3+g)*8+kc][lane][8]  -> 16*3*8*512 = 196608 u16   (bf16 hi only)
//   IH: frag[(nt*3+g)*4+kc][lane][8]  -> 16*3*4*512 =  98304 u16
// frag content (B-operand): W[g*256 + nt*16 + (lane&15)][kc*32 + (lane>>4)*8 + j]
#define PK_HHD (16*3*8*512)                 // 196608
#define PK_IHD (16*3*4*512)                 // 98304
#define DIR_U16 (PK_HHD + PK_IHD)           // 294912
#define EMB_OFF_U16 (2*DIR_U16)             // 589824
#define EMB_U16 (VOCABN*EE)                 // 33536
#define BIAS_OFF_U16 (EMB_OFF_U16 + EMB_U16) // 623360 (byte 1246720, 4-aligned)
// bias region: per dir 1024 f32: [0..511]=bih+bhh (r,z) ; [512..767]=bih_n ; [768..1023]=bhh_n

__device__ __forceinline__ float bf2f(u16 u){ union{u32 i; float f;} v; v.i=((u32)u)<<16; return v.f; }
__device__ __forceinline__ u16 f2bf(float f){
  __hip_bfloat16 h = __float2bfloat16(f);   // rne
  u16 r; __builtin_memcpy(&r, &h, 2); return r;
}
__device__ __forceinline__ float sigmoid_f(float x){
  float e = __builtin_amdgcn_exp2f(-1.4426950408889634f * x);
  return __builtin_amdgcn_rcpf(1.0f + e);
}
__device__ __forceinline__ float tanh_f(float x){
  float ax = __builtin_fabsf(x);
  float e  = __builtin_amdgcn_exp2f(-2.8853900817779268f * ax);
  float t  = 1.0f - 2.0f * e * __builtin_amdgcn_rcpf(1.0f + e);
  return __builtin_copysignf(t, x);
}

// ---- pack weights into per-wave MFMA B-fragment order (bf16 hi only) ----
__global__ void prep_pack(const float* __restrict__ Wih_fw, const float* __restrict__ Whh_fw,
                          const float* __restrict__ Wih_bw, const float* __restrict__ Whh_bw,
                          u16* __restrict__ wsu)
{
  int idx = blockIdx.x*256 + threadIdx.x;       // grid exact: 2*DIR_U16/256 = 2304 blocks
  int d = idx / DIR_U16;
  int r = idx - d*DIR_U16;
  const float* Whh = d ? Whh_bw : Whh_fw;
  const float* Wih = d ? Wih_bw : Wih_fw;
  u16 outv;
  if (r < PK_HHD) {
    int e = r;
    int jj   = e & 7;
    int lane = (e >> 3) & 63;
    int kc   = (e >> 9) & 7;
    int gnt  = e >> 12;                // nt*3+g, < 48
    int g = gnt % 3, nt = gnt / 3;
    int row = g*256 + nt*16 + (lane & 15);
    int k   = kc*32 + ((lane >> 4) << 3) + jj;
    outv = f2bf(Whh[row*HHH + k]);
  } else {
    int e = r - PK_HHD;
    int jj   = e & 7;
    int lane = (e >> 3) & 63;
    int kc   = (e >> 9) & 3;
    int gnt  = e >> 11;                // < 48
    int g = gnt % 3, nt = gnt / 3;
    int row = g*256 + nt*16 + (lane & 15);
    int k   = kc*32 + ((lane >> 4) << 3) + jj;
    outv = f2bf(Wih[row*EE + k]);
  }
  wsu[idx] = outv;
}

// ---- bf16 embed table + fused biases ----
__global__ void prep_misc(const float* __restrict__ emb,
                          const float* __restrict__ bih_fw, const float* __restrict__ bhh_fw,
                          const float* __restrict__ bih_bw, const float* __restrict__ bhh_bw,
                          u16* __restrict__ wsu)
{
  int i = blockIdx.x*256 + threadIdx.x;
  if (i < EMB_U16) { wsu[EMB_OFF_U16 + i] = f2bf(emb[i]); return; }
  int b = i - EMB_U16;
  if (b >= 2048) return;
  int d = b >> 10, o = b & 1023;
  const float* bih = d ? bih_bw : bih_fw;
  const float* bhh = d ? bhh_bw : bhh_fw;
  float v;
  if (o < 512)      v = bih[o] + bhh[o];
  else if (o < 768) v = bih[o - 512 + 512];   // bih_n
  else              v = bhh[o - 768 + 512];   // bhh_n
  ((float*)(wsu + BIAS_OFF_U16))[d*1024 + o] = v;
}

__global__ __launch_bounds__(1024)
void gru_mfma(const int* __restrict__ chars, const int* __restrict__ chars_mask,
              const int* __restrict__ data_mask, const u16* __restrict__ wsu,
              float* __restrict__ out)
{
  const int dir   = blockIdx.x & 1;           // XCD parity: one dir per XCD
  const int word0 = (blockIdx.x >> 1) * MMW;
  const int j     = threadIdx.x;              // 0..1023 = 16 waves (4 per SIMD)
  const int wave  = j >> 6, lane = j & 63;
  const int quad  = lane >> 4, l15 = lane & 15;

  const u16* wbase = wsu + (size_t)dir*DIR_U16;
  const bf16x8* pHH = (const bf16x8*)wbase;             // [(nt*3+g)*8+kc][64]
  const bf16x8* pIH = (const bf16x8*)(wbase + PK_HHD);  // [(nt*3+g)*4+kc][64]
  const u16*    embbf = wsu + EMB_OFF_U16;
  const float*  bias  = (const float*)(wsu + BIAS_OFF_U16) + dir*1024;

  // this wave owns gate-tile nt == wave (16 output channels)
  const bf16x8* bHH = pHH + (size_t)(wave*3)*8*64 + lane;
  const bf16x8* bIH = pIH + (size_t)(wave*3)*4*64 + lane;

  __shared__ __align__(16) u16   sh_hhi[MMW][HS];     // bf16 hi of h, A-layout (34.8 KB)
  __shared__ __align__(16) u16   sh_hlo[MMW][HS];     // bf16 lo of h           (34.8 KB)
  __shared__ __align__(16) u16   sh_x[MMW][XS];       // x_t bf16               (18.4 KB)
  __shared__ float sh_m[MMW];

  for (int i = j; i < MMW*HS/2; i += 1024) { ((float*)sh_hhi)[i] = 0.0f; ((float*)sh_hlo)[i] = 0.0f; }

  const int ch = wave*16 + l15;             // this lane's output channel
  const float bR  = bias[ch],        bZ  = bias[256 + ch];
  const float bXN = bias[512 + ch],  bHN = bias[768 + ch];

  const int sw = j >> 4, sp = j & 15;       // x-staging: word (64), 8-u16 part (16)

  // 12 weight batches per step: b in [0,4) = IH kc=b ; b in [4,12) = HH kc=b-4.
  // Each batch = 3 frags (one nt, 3 gates). Double-buffered; addresses are
  // step-invariant, so batches 0..1 of step s+1 are pre-issued before the
  // epilogue barrier of step s.
  bf16x8 buf[2][3];

  auto load_batch = [&](int b, bf16x8 dst[3]) {
    if (b < 4) {
      const int kc = b;
      #pragma unroll
      for (int g = 0; g < 3; ++g) dst[g] = bIH[(g*4 + kc)*64];
    } else {
      const int kc = b - 4;
      #pragma unroll
      for (int g = 0; g < 3; ++g) dst[g] = bHH[(g*8 + kc)*64];
    }
  };

  load_batch(0, buf[0]);
  load_batch(1, buf[1]);

  #pragma unroll 1
  for (int s = 0; s < CC; ++s) {
    const int t = dir ? (CC - 1 - s) : s;
    __syncthreads();                                   // S0: h writes visible, prev x reads done
    {
      int ci = chars[(word0 + sw)*CC + t];
      *(uint4*)&sh_x[sw][sp*8] = *(const uint4*)(embbf + (size_t)ci*EE + sp*8);
      if (j < MMW) sh_m[j] = (float)chars_mask[(word0 + j)*CC + t];
    }
    __syncthreads();                                   // S1: x/mask staged

    // acc[0]=r, acc[1]=z, acc[2]=xn, acc[3]=hn ; [m-tile 0..3]  (64 regs)
    f32x4 acc[4][4];
    #pragma unroll
    for (int m = 0; m < 4; ++m) {
      acc[0][m] = (f32x4){bR,bR,bR,bR};
      acc[1][m] = (f32x4){bZ,bZ,bZ,bZ};
      acc[2][m] = (f32x4){bXN,bXN,bXN,bXN};
      acc[3][m] = (f32x4){bHN,bHN,bHN,bHN};
    }

    auto mfma_batch = [&](int b, bf16x8 src[3]) {
      if (b < 4) {
        const int kc = b;
        #pragma unroll
        for (int m = 0; m < 4; ++m) {
          bf16x8 ax = *(const bf16x8*)&sh_x[m*16 + l15][kc*32 + quad*8];
          #pragma unroll
          for (int g = 0; g < 3; ++g) {
            const int ai = (g < 2) ? g : 2;
            acc[ai][m] = __builtin_amdgcn_mfma_f32_16x16x32_bf16(ax, src[g], acc[ai][m], 0,0,0);
          }
        }
      } else {
        const int kc = b - 4;
        #pragma unroll
        for (int m = 0; m < 4; ++m) {
          bf16x8 ah = *(const bf16x8*)&sh_hhi[m*16 + l15][kc*32 + quad*8];
          bf16x8 al = *(const bf16x8*)&sh_hlo[m*16 + l15][kc*32 + quad*8];
          #pragma unroll
          for (int g = 0; g < 3; ++g) {
            const int ai = (g < 2) ? g : 3;
            acc[ai][m] = __builtin_amdgcn_mfma_f32_16x16x32_bf16(ah, src[g], acc[ai][m], 0,0,0);
            acc[ai][m] = __builtin_amdgcn_mfma_f32_16x16x32_bf16(al, src[g], acc[ai][m], 0,0,0);
          }
        }
      }
    };

    #pragma unroll
    for (int b = 0; b < 12; ++b) {
      mfma_batch(b, buf[b & 1]);
      if (b < 10) load_batch(b + 2, buf[b & 1]);
      else load_batch(b - 10, buf[b & 1]);             // pre-issue next step's 0,1
    }

    __syncthreads();                                   // S2: all h/x fragment reads done

    // ---- gate math + h update (lane owns (word, ch) pairs) ----
    #pragma unroll
    for (int m = 0; m < 4; ++m)
      #pragma unroll
      for (int r = 0; r < 4; ++r) {
        const int word = m*16 + quad*4 + r;
        float rr = sigmoid_f(acc[0][m][r]);
        float zz = sigmoid_f(acc[1][m][r]);
        float nn = tanh_f(fmaf(rr, acc[3][m][r], acc[2][m][r]));
        float hold = bf2f(sh_hhi[word][ch]) + bf2f(sh_hlo[word][ch]);
        float hnew = fmaf(zz, hold - nn, nn);              // (1-z)*n + z*h
        float hm   = fmaf(sh_m[word], hnew - hold, hold);  // mask freeze
        u16 hi = f2bf(hm);
        sh_hhi[word][ch] = hi;
        sh_hlo[word][ch] = f2bf(hm - bf2f(hi));
      }
  }
  __syncthreads();

  // ---- output: 64 words x 256 ch, coalesced fp32 ----
  const int oc = j & 255, og = j >> 8;     // 4 groups of 16 words
  #pragma unroll
  for (int i = 0; i < 16; ++i) {
    const int w = og*16 + i;
    float dm = (float)data_mask[word0 + w];
    float h = bf2f(sh_hhi[w][oc]) + bf2f(sh_hlo[w][oc]);
    out[(size_t)(word0 + w)*(2*HHH) + dir*HHH + oc] = h * dm;
  }
}

extern "C" void kernel_launch(void* const* d_in, const int* in_sizes, int n_in,
                              void* d_out, int out_size, void* d_ws, size_t ws_size,
                              hipStream_t stream) {
  const int*   chars      = (const int*)d_in[0];
  const int*   chars_mask = (const int*)d_in[1];
  const int*   data_mask  = (const int*)d_in[2];
  const float* embed      = (const float*)d_in[3];
  const float* Wih_fw     = (const float*)d_in[4];
  const float* Whh_fw     = (const float*)d_in[5];
  const float* bih_fw     = (const float*)d_in[6];
  const float* bhh_fw     = (const float*)d_in[7];
  const float* Wih_bw     = (const float*)d_in[8];
  const float* Whh_bw     = (const float*)d_in[9];
  const float* bih_bw     = (const float*)d_in[10];
  const float* bhh_bw     = (const float*)d_in[11];
  u16* wsu = (u16*)d_ws;

  prep_pack<<<2*DIR_U16/256, 256, 0, stream>>>(Wih_fw, Whh_fw, Wih_bw, Whh_bw, wsu);
  prep_misc<<<(EMB_U16 + 2048 + 255)/256, 256, 0, stream>>>(embed, bih_fw, bhh_fw, bih_bw, bhh_bw, wsu);

  // 128 blocks: (word-group, dir) packed so dir == blockIdx&1 (XCD parity)
  gru_mfma<<<(NWORDS/MMW)*2, 1024, 0, stream>>>(chars, chars_mask, data_mask, wsu, (float*)d_out);
}

// Round 12
// 432.815 us; speedup vs baseline: 1.9635x; 1.9635x over previous
//
#include <hip/hip_runtime.h>
#include <hip/hip_bf16.h>

typedef unsigned int u32;
typedef unsigned short u16;
typedef __attribute__((ext_vector_type(8))) short bf16x8;
typedef __attribute__((ext_vector_type(4))) float f32x4;

// Problem constants
#define NWORDS 4096   // B*S
#define CC 32         // chars per word
#define EE 128        // embed dim
#define HHH 256       // hidden
#define MMW 32        // words per block (2 m-tiles per wave)
#define VOCABN 262

// LDS row strides (dwords % 32 == 8 -> low-way b128 conflicts)
#define HS 272        // u16 stride for h arrays (136 dw)
#define XPS 784       // u16 stride for xp rows  (392 dw, 392%32=8)

// Workspace layout (u16 units):
//   HH pack per dir: frag[(nt*3+g)*8+kc][lane][8] -> 16*3*8*512 = 196608 u16 (bf16 hi of Whh)
//   XP table per dir: [262][768] bf16 = embed @ Wih^T (no bias)
//   bias: per dir 1024 f32: [0..511]=bih+bhh(r,z); [512..767]=bih_n; [768..1023]=bhh_n
#define PK_HHD (16*3*8*512)                  // 196608
#define XP_OFF_U16 (2*PK_HHD)                // 393216
#define XPD (VOCABN*768)                     // 201216
#define BIAS_OFF_U16 (XP_OFF_U16 + 2*XPD)    // 795648 (byte 1591296, 4-aligned)

__device__ __forceinline__ float bf2f(u16 u){ union{u32 i; float f;} v; v.i=((u32)u)<<16; return v.f; }
__device__ __forceinline__ u16 f2bf(float f){
  __hip_bfloat16 h = __float2bfloat16(f);   // rne
  u16 r; __builtin_memcpy(&r, &h, 2); return r;
}
__device__ __forceinline__ float sigmoid_f(float x){
  float e = __builtin_amdgcn_exp2f(-1.4426950408889634f * x);
  return __builtin_amdgcn_rcpf(1.0f + e);
}
__device__ __forceinline__ float tanh_f(float x){
  float ax = __builtin_fabsf(x);
  float e  = __builtin_amdgcn_exp2f(-2.8853900817779268f * ax);
  float t  = 1.0f - 2.0f * e * __builtin_amdgcn_rcpf(1.0f + e);
  return __builtin_copysignf(t, x);
}

// ---- pack Whh into per-wave MFMA B-fragment order (bf16 hi only) ----
__global__ void prep_pack(const float* __restrict__ Whh_fw, const float* __restrict__ Whh_bw,
                          u16* __restrict__ wsu)
{
  int idx = blockIdx.x*256 + threadIdx.x;       // grid exact: 2*PK_HHD/256 = 1536 blocks
  int d = idx / PK_HHD;
  int e = idx - d*PK_HHD;
  const float* Whh = d ? Whh_bw : Whh_fw;
  int jj   = e & 7;
  int lane = (e >> 3) & 63;
  int kc   = (e >> 9) & 7;
  int gnt  = e >> 12;                // nt*3+g, < 48
  int g = gnt % 3, nt = gnt / 3;
  int row = g*256 + nt*16 + (lane & 15);
  int k   = kc*32 + ((lane >> 4) << 3) + jj;
  wsu[idx] = f2bf(Whh[row*HHH + k]);
}

// ---- XP table: XP[d][c][g] = sum_e embed[c][e] * Wih_d[g][e]  (fp32 math, bf16 store) ----
__global__ void prep_xp(const float* __restrict__ emb,
                        const float* __restrict__ Wih_fw, const float* __restrict__ Wih_bw,
                        u16* __restrict__ wsu)
{
  int i = blockIdx.x*256 + threadIdx.x;         // grid exact: 2*XPD/256 = 1572 blocks
  int d = i / XPD;
  int r = i - d*XPD;
  int c = r / 768, g = r - c*768;
  const float* W = (d ? Wih_bw : Wih_fw) + g*EE;
  const float* E = emb + c*EE;
  float acc = 0.0f;
  #pragma unroll 4
  for (int e = 0; e < EE; e += 4) {
    float4 ev = *(const float4*)(E + e);
    float4 wv = *(const float4*)(W + e);
    acc = fmaf(ev.w, wv.w, fmaf(ev.z, wv.z, fmaf(ev.y, wv.y, fmaf(ev.x, wv.x, acc))));
  }
  wsu[XP_OFF_U16 + i] = f2bf(acc);
}

// ---- fused biases ----
__global__ void prep_bias(const float* __restrict__ bih_fw, const float* __restrict__ bhh_fw,
                          const float* __restrict__ bih_bw, const float* __restrict__ bhh_bw,
                          u16* __restrict__ wsu)
{
  int i = blockIdx.x*256 + threadIdx.x;
  if (i >= 2048) return;
  int d = i >> 10, o = i & 1023;
  const float* bih = d ? bih_bw : bih_fw;
  const float* bhh = d ? bhh_bw : bhh_fw;
  float v;
  if (o < 512)      v = bih[o] + bhh[o];
  else if (o < 768) v = bih[o - 512 + 512];   // bih_n
  else              v = bhh[o - 768 + 512];   // bhh_n
  ((float*)(wsu + BIAS_OFF_U16))[d*1024 + o] = v;
}

__global__ __launch_bounds__(1024)
void gru_mfma(const int* __restrict__ chars, const int* __restrict__ chars_mask,
              const int* __restrict__ data_mask, const u16* __restrict__ wsu,
              float* __restrict__ out)
{
  const int dir   = blockIdx.x & 1;           // XCD parity: one dir per XCD
  const int word0 = (blockIdx.x >> 1) * MMW;
  const int j     = threadIdx.x;              // 0..1023 = 16 waves (4 per SIMD)
  const int wave  = j >> 6, lane = j & 63;
  const int quad  = lane >> 4, l15 = lane & 15;

  const bf16x8* pHH  = (const bf16x8*)(wsu + (size_t)dir*PK_HHD);
  const u16*    xpt  = wsu + XP_OFF_U16 + (size_t)dir*XPD;
  const float*  bias = (const float*)(wsu + BIAS_OFF_U16) + dir*1024;

  // this wave owns gate-tile nt == wave (16 output channels)
  const bf16x8* bHH = pHH + (size_t)(wave*3)*8*64 + lane;

  __shared__ __align__(16) u16   sh_hhi[MMW][HS];     // bf16 hi of h, A-layout (17.4 KB)
  __shared__ __align__(16) u16   sh_hlo[MMW][HS];     // bf16 lo of h           (17.4 KB)
  __shared__ __align__(16) u16   sh_xp[MMW][XPS];     // xp rows (768 used)     (50.2 KB)
  __shared__ float sh_m[MMW];

  for (int i = j; i < MMW*HS/2; i += 1024) { ((float*)sh_hhi)[i] = 0.0f; ((float*)sh_hlo)[i] = 0.0f; }

  const int ch = wave*16 + l15;             // this lane's output channel
  const float bR  = bias[ch],        bZ  = bias[256 + ch];
  const float bXN = bias[512 + ch],  bHN = bias[768 + ch];

  const int sw = j >> 5, sp = j & 31;       // xp-staging: word (32), 24-u16 part (32)

  // 8 HH batches per step (kc 0..7), 3 frags each. FOUR buffer slots so the
  // rotation is step-aligned (8 % 4 == 0): batch b lives in slot b&3, and the
  // tail loads of a step pre-issue the next step's kc 0..2 into slots 0..2 --
  // restoring the initial-state invariant every step. (3 slots broke this:
  // 8 % 3 != 0 permuted kc across steps => R11's 5.2e-2 failure.)
  bf16x8 buf[4][3];
  auto load_batch = [&](int kc, bf16x8 dst[3]) {
    #pragma unroll
    for (int g = 0; g < 3; ++g) dst[g] = bHH[(g*8 + kc)*64];
  };
  load_batch(0, buf[0]);
  load_batch(1, buf[1]);
  load_batch(2, buf[2]);

  #pragma unroll 1
  for (int s = 0; s < CC; ++s) {
    const int t = dir ? (CC - 1 - s) : s;
    __syncthreads();                                   // S0: h writes visible, prev xp reads done
    {
      int ci = chars[(word0 + sw)*CC + t];
      const uint4* src = (const uint4*)(xpt + (size_t)ci*768);   // 96 uint4 per row
      uint4 a0 = src[sp*3], a1 = src[sp*3+1], a2 = src[sp*3+2];
      *(uint4*)&sh_xp[sw][sp*24]      = a0;
      *(uint4*)&sh_xp[sw][sp*24 + 8]  = a1;
      *(uint4*)&sh_xp[sw][sp*24 + 16] = a2;
      if (j < MMW) sh_m[j] = (float)chars_mask[(word0 + j)*CC + t];
    }
    __syncthreads();                                   // S1: xp/mask staged

    // acc[0]=r, acc[1]=z, acc[2]=hn ; [m-tile]  (24 regs)
    f32x4 acc[3][2];
    #pragma unroll
    for (int m = 0; m < 2; ++m) {
      acc[0][m] = (f32x4){bR,bR,bR,bR};
      acc[1][m] = (f32x4){bZ,bZ,bZ,bZ};
      acc[2][m] = (f32x4){bHN,bHN,bHN,bHN};
    }

    auto mfma_batch = [&](int kc, bf16x8 src[3]) {
      #pragma unroll
      for (int m = 0; m < 2; ++m) {
        bf16x8 ah = *(const bf16x8*)&sh_hhi[m*16 + l15][kc*32 + quad*8];
        bf16x8 al = *(const bf16x8*)&sh_hlo[m*16 + l15][kc*32 + quad*8];
        #pragma unroll
        for (int g = 0; g < 3; ++g) {
          const int ai = (g < 2) ? g : 2;
          acc[ai][m] = __builtin_amdgcn_mfma_f32_16x16x32_bf16(ah, src[g], acc[ai][m], 0,0,0);
          acc[ai][m] = __builtin_amdgcn_mfma_f32_16x16x32_bf16(al, src[g], acc[ai][m], 0,0,0);
        }
      }
    };

    #pragma unroll
    for (int b = 0; b < 8; ++b) {
      mfma_batch(b, buf[b & 3]);
      load_batch((b + 3) & 7, buf[(b + 3) & 3]);       // b>=5 pre-issues next step's 0,1,2
    }

    __syncthreads();                                   // S2: all h fragment reads done

    // ---- gate math + h update (lane owns (word, ch) pairs) ----
    #pragma unroll
    for (int m = 0; m < 2; ++m)
      #pragma unroll
      for (int r = 0; r < 4; ++r) {
        const int word = m*16 + quad*4 + r;
        float xr = bf2f(sh_xp[word][ch]);
        float xz = bf2f(sh_xp[word][256 + ch]);
        float xn = bf2f(sh_xp[word][512 + ch]);
        float rr = sigmoid_f(acc[0][m][r] + xr);
        float zz = sigmoid_f(acc[1][m][r] + xz);
        float nn = tanh_f(fmaf(rr, acc[2][m][r], bXN + xn));
        float hold = bf2f(sh_hhi[word][ch]) + bf2f(sh_hlo[word][ch]);
        float hnew = fmaf(zz, hold - nn, nn);              // (1-z)*n + z*h
        float hm   = fmaf(sh_m[word], hnew - hold, hold);  // mask freeze
        u16 hi = f2bf(hm);
        sh_hhi[word][ch] = hi;
        sh_hlo[word][ch] = f2bf(hm - bf2f(hi));
      }
  }
  __syncthreads();

  // ---- output: 32 words x 256 ch, coalesced fp32 ----
  const int oc = j & 255, og = j >> 8;     // 4 groups of 8 words
  #pragma unroll
  for (int i = 0; i < 8; ++i) {
    const int w = og*8 + i;
    float dm = (float)data_mask[word0 + w];
    float h = bf2f(sh_hhi[w][oc]) + bf2f(sh_hlo[w][oc]);
    out[(size_t)(word0 + w)*(2*HHH) + dir*HHH + oc] = h * dm;
  }
}

extern "C" void kernel_launch(void* const* d_in, const int* in_sizes, int n_in,
                              void* d_out, int out_size, void* d_ws, size_t ws_size,
                              hipStream_t stream) {
  const int*   chars      = (const int*)d_in[0];
  const int*   chars_mask = (const int*)d_in[1];
  const int*   data_mask  = (const int*)d_in[2];
  const float* embed      = (const float*)d_in[3];
  const float* Wih_fw     = (const float*)d_in[4];
  const float* Whh_fw     = (const float*)d_in[5];
  const float* bih_fw     = (const float*)d_in[6];
  const float* bhh_fw     = (const float*)d_in[7];
  const float* Wih_bw     = (const float*)d_in[8];
  const float* Whh_bw     = (const float*)d_in[9];
  const float* bih_bw     = (const float*)d_in[10];
  const float* bhh_bw     = (const float*)d_in[11];
  u16* wsu = (u16*)d_ws;

  prep_pack<<<2*PK_HHD/256, 256, 0, stream>>>(Whh_fw, Whh_bw, wsu);
  prep_xp<<<2*XPD/256, 256, 0, stream>>>(embed, Wih_fw, Wih_bw, wsu);
  prep_bias<<<8, 256, 0, stream>>>(bih_fw, bhh_fw, bih_bw, bhh_bw, wsu);

  // 256 blocks: (word-group, dir) packed so dir == blockIdx&1 (XCD parity)
  gru_mfma<<<(NWORDS/MMW)*2, 1024, 0, stream>>>(chars, chars_mask, data_mask, wsu, (float*)d_out);
}